// Round 7
// baseline (116.721 us; speedup 1.0000x reference)
//
#include <hip/hip_runtime.h>

#define FRAME 160
#define ORDER 12
#define NFRAMES (4096 * 15)
#define EPL 10            // elements per sub-lane (16 lanes per frame-pair)
#define ROWK1 162         // k1 row: 161 pairs (p=0..160, tail zero) + align pad
#define PADF 12
#define ROWP 174          // k2 row: 12 front pad + 160 + 1 zero tail + 1 align pad

typedef float v2f __attribute__((ext_vector_type(2)));

__device__ __forceinline__ v2f pkfma(v2f a, v2f b, v2f c) {
    return __builtin_elementwise_fma(a, b, c);
}
__device__ __forceinline__ v2f splat2(float v) { v2f r; r.x = v; r.y = v; return r; }

template<int CTRL>
__device__ __forceinline__ float dppf(float v) {
    return __int_as_float(__builtin_amdgcn_update_dpp(
        0, __float_as_int(v), CTRL, 0xF, 0xF, true));
}
__device__ __forceinline__ float rowsum16(float v) {
    v += dppf<0xB1>(v);    // lane ^= 1
    v += dppf<0x4E>(v);    // lane ^= 2
    v += dppf<0x140>(v);   // row_mirror
    v += dppf<0x141>(v);   // row_half_mirror
    return v;
}
__device__ __forceinline__ v2f rowsum16v(v2f v) {
    v2f r; r.x = rowsum16(v.x); r.y = rowsum16(v.y); return r;
}

// ---------------- Kernel 1: windowed Burg LPC -> coeffs to d_ws -------------
__global__ __launch_bounds__(256) void burg_k1(
    const float* __restrict__ pcm, float* __restrict__ acoef)
{
    const int tid  = threadIdx.x;
    const int wave = tid >> 6;
    const int lane = tid & 63;
    const int g    = lane >> 4;
    const int s    = lane & 15;
    const int Gid  = (blockIdx.x * 4 + wave) * 4 + g;   // global frame-pair id
    const int fA   = 2 * Gid, fB = fA + 1;

    __shared__ __align__(16) v2f s_x[4][4][ROWK1];   // 20.7 KB
    __shared__ float s_win[161];

    if (tid < 161) {
        float w = (tid < 160)
            ? 0.5f - 0.5f * __cosf(6.2831853071795864769f / 159.0f * (float)tid)
            : 0.0f;
        s_win[tid] = w;
    }
    if (lane < 4) s_x[wave][lane][160] = splat2(0.f);   // tail zero (p=160)
    {
        const float* pAg = pcm + (size_t)fA * FRAME;
        const float* pBg = pcm + (size_t)fB * FRAME;
#pragma unroll
        for (int c = 0; c < 3; ++c) {
            int p = 4 * s + 64 * c;
            if (p < FRAME) {
                float4 a4 = *(const float4*)(pAg + p);
                float4 b4 = *(const float4*)(pBg + p);
                float4* dst = (float4*)&s_x[wave][g][p];   // 16B aligned (p%4==0)
                dst[0] = make_float4(a4.x, b4.x, a4.y, b4.y);
                dst[1] = make_float4(a4.z, b4.z, a4.w, b4.w);
            }
        }
    }
    __syncthreads();

    const v2f* X = &s_x[wave][g][0];
    const int p0 = s * EPL;

    v2f F[EPL], B[EPL];
    {
        v2f pr[EPL + 1];
#pragma unroll
        for (int j = 0; j <= EPL; ++j)
            pr[j] = X[p0 + j] * s_win[p0 + j];
#pragma unroll
        for (int t = 0; t < EPL; ++t) { F[t] = pr[t + 1]; B[t] = pr[t]; }
    }
    if (s == 15) B[EPL - 1] = splat2(0.f);
    v2f dpF = splat2(0.f), dpB = splat2(0.f);
#pragma unroll
    for (int t = 0; t < EPL; ++t) {
        dpF = pkfma(F[t], F[t], dpF);
        dpB = pkfma(B[t], B[t], dpB);
    }
    v2f den = rowsum16v(dpF + dpB);

    v2f a  = (s == 0) ? splat2(1.f) : splat2(0.f);
    v2f ar = (s == 1) ? splat2(1.f) : splat2(0.f);
    v2f cp = splat2(0.f), dsc = splat2(0.f);

#pragma unroll
    for (int i = 0; i < ORDER; ++i) {
        v2f q0 = splat2(0.f), q1 = splat2(0.f);
#pragma unroll
        for (int t = 0; t < EPL; t += 2) {
            q0 = pkfma(F[t],     B[t],     q0);
            q1 = pkfma(F[t + 1], B[t + 1], q1);
        }
        v2f num = rowsum16v(q0 + q1);
        if (i > 0) den = dsc - rowsum16v(cp);
        v2f r;
        r.x = -2.0f * num.x * __builtin_amdgcn_rcpf(den.x);
        r.y = -2.0f * num.y * __builtin_amdgcn_rcpf(den.y);

        v2f an  = pkfma(r, ar, a);
        v2f arn = pkfma(r, a, ar);
        a = an;
        ar.x = dppf<0x111>(arn.x);       // row_shr:1, lane0 <- 0
        ar.y = dppf<0x111>(arn.y);

#pragma unroll
        for (int t = 0; t < EPL; ++t) {
            v2f fo = F[t];
            F[t] = pkfma(r, B[t], fo);
            B[t] = pkfma(r, fo, B[t]);
        }

        const int pe = 158 - i;
        const int SL = pe / EPL, SS = pe % EPL;
        v2f fe = (s == 0)  ? F[0]  : splat2(0.f);
        v2f be = (s == SL) ? B[SS] : splat2(0.f);
        cp  = pkfma(fe, fe, be * be);
        dsc = pkfma(-(r * r), den, den);

        v2f up;
        up.x = dppf<0x101>(F[0].x);      // row_shl:1, lane15 -> 0
        up.y = dppf<0x101>(F[0].y);
#pragma unroll
        for (int t = 0; t < EPL - 1; ++t) F[t] = F[t + 1];
        F[EPL - 1] = up;
        if (s == SL) B[SS] = splat2(0.f);
    }

    // Coeffs out: 13 packed pairs per group, contiguous 104B (coalesced).
    if (s < ORDER + 1)
        *(v2f*)(acoef + 2 * ((size_t)Gid * (ORDER + 1) + s)) = a;
}

// ---------------- Kernel 2: FIR residual + embed (memory-streaming) ---------
__global__ __launch_bounds__(256) void fir_k2(
    const int* __restrict__ bits, const float* __restrict__ pcm,
    const float* __restrict__ alpha_p, const float* __restrict__ acoef,
    float* __restrict__ out)
{
    const int tid  = threadIdx.x;
    const int wave = tid >> 6;
    const int lane = tid & 63;
    const int g    = lane >> 4;
    const int s    = lane & 15;
    const int Gid  = (blockIdx.x * 4 + wave) * 4 + g;
    const int fA   = 2 * Gid, fB = fA + 1;

    __shared__ __align__(16) v2f s_x[4][4][ROWP];    // 22.3 KB
    __shared__ v2f s_a[4][4][16];

    // a-coeff fetch (8B/lane, 104B contiguous per group) + bounce via LDS.
    if (s < ORDER + 1)
        s_a[wave][g][s] = *(const v2f*)(acoef + 2 * ((size_t)Gid * (ORDER + 1) + s));
    // Zero front pads and tail pad.
    if (lane < 48) { int gr = lane / 12, j = lane % 12; s_x[wave][gr][j] = splat2(0.f); }
    if (lane < 4)  s_x[wave][lane][PADF + FRAME] = splat2(0.f);
    {
        const float* pAg = pcm + (size_t)fA * FRAME;
        const float* pBg = pcm + (size_t)fB * FRAME;
#pragma unroll
        for (int c = 0; c < 3; ++c) {
            int p = 4 * s + 64 * c;
            if (p < FRAME) {
                float4 a4 = *(const float4*)(pAg + p);
                float4 b4 = *(const float4*)(pBg + p);
                float4* dst = (float4*)&s_x[wave][g][PADF + p];
                dst[0] = make_float4(a4.x, b4.x, a4.y, b4.y);
                dst[1] = make_float4(a4.z, b4.z, a4.w, b4.w);
            }
        }
    }
    __syncthreads();

    const v2f* X = &s_x[wave][g][PADF];
    const int p0 = s * EPL;

    v2f ak[ORDER + 1];
#pragma unroll
    for (int k = 0; k <= ORDER; ++k) ak[k] = s_a[wave][g][k];

    v2f Xw[EPL + ORDER];
#pragma unroll
    for (int j = 0; j < EPL + ORDER; ++j) Xw[j] = X[p0 - ORDER + j];

    const float alpha = alpha_p[0];
    v2f ac;
    ac.x = alpha * (2.0f * (float)bits[fA] - 1.0f);
    ac.y = alpha * (2.0f * (float)bits[fB] - 1.0f);

    float* oA = out + (size_t)fA * FRAME + p0;
    float* oB = out + (size_t)fB * FRAME + p0;
#pragma unroll
    for (int t = 0; t < EPL; t += 2) {
        v2f acc0 = splat2(0.f), acc1 = splat2(0.f);
#pragma unroll
        for (int k = 0; k <= ORDER; ++k) {
            acc0 = pkfma(ak[k], Xw[ORDER + t - k],     acc0);
            acc1 = pkfma(ak[k], Xw[ORDER + t + 1 - k], acc1);
        }
        v2f r0 = pkfma(ac, acc0, Xw[ORDER + t]);
        v2f r1 = pkfma(ac, acc1, Xw[ORDER + t + 1]);
        *(float2*)(oA + t) = make_float2(r0.x, r1.x);
        *(float2*)(oB + t) = make_float2(r0.y, r1.y);
    }
}

extern "C" void kernel_launch(void* const* d_in, const int* in_sizes, int n_in,
                              void* d_out, int out_size, void* d_ws, size_t ws_size,
                              hipStream_t stream) {
    const int*   bits  = (const int*)d_in[0];
    const float* pcm   = (const float*)d_in[1];
    const float* alpha = (const float*)d_in[2];
    float*       out   = (float*)d_out;
    float*       acoef = (float*)d_ws;   // 30720 pairs x 13 x 8B = 3.2 MB

    dim3 grid(NFRAMES / 32), block(256);
    hipLaunchKernelGGL(burg_k1, grid, block, 0, stream, pcm, acoef);
    hipLaunchKernelGGL(fir_k2,  grid, block, 0, stream, bits, pcm, alpha, acoef, out);
}